// Round 1
// baseline (294.104 us; speedup 1.0000x reference)
//
#include <hip/hip_runtime.h>

#define NN 25600      // nodes = 160*160
#define HH 160
#define WW 160
#define C2 256

// ---- bf16 weight pack offsets (ushorts) ----
#define B_WIN   0
#define B_WID   32768
#define B_WGAT  65536      // 2 layers x 65536
#define B_WOUT  196608
#define B_WEND  262144

// ---- small fp32 param offsets inside cvt (floats) ----
#define C_BNA   0          // 2x256 BN scale
#define C_BNB   512        // 2x256 BN shift (bias/mean folded)
#define C_ASRC  1024       // 2x256
#define C_ADST  1536       // 2x256
#define C_SEW1  2048       // 64x256
#define C_SEB1  18432      // 64
#define C_SEW2  18496      // 256x64
#define C_SEB2  34880      // 256
#define C_END   35136

typedef __attribute__((ext_vector_type(8))) short bfrag;   // 8 bf16 (4 VGPRs)
typedef __attribute__((ext_vector_type(4))) float ffrag;   // 4 fp32 acc

__device__ __forceinline__ float b2f(unsigned short u) {
    union { unsigned int ui; float f; } v; v.ui = ((unsigned int)u) << 16; return v.f;
}
__device__ __forceinline__ unsigned short f2b(float f) {
    union { float f; unsigned int u; } v; v.f = f;
    unsigned int u = v.u;
    unsigned int r = (u + 0x7FFFu + ((u >> 16) & 1u)) >> 16;
    return (unsigned short)r;
}
__device__ __forceinline__ float lo16f(unsigned int w) {
    union { unsigned int ui; float f; } v; v.ui = w << 16; return v.f;
}
__device__ __forceinline__ float hi16f(unsigned int w) {
    union { unsigned int ui; float f; } v; v.ui = w & 0xFFFF0000u; return v.f;
}
// Wave-uniform dtype probe on first 512 halfwords of x.
__device__ __forceinline__ bool probe_f32(const unsigned short* __restrict__ x) {
    int l = threadIdx.x & 63;
    bool wild = false;
#pragma unroll
    for (int i = 0; i < 8; ++i) {
        float v = b2f(x[l * 8 + i]);
        wild |= !(fabsf(v) < 1e6f);
    }
    return __any(wild);
}
__device__ __forceinline__ float ldf(const void* p, long i, bool f32) {
    return f32 ? ((const float*)p)[i] : b2f(((const unsigned short*)p)[i]);
}

// ---------------------------------------------------------------------------
// prep: pack weights bf16, fold BN, convert small params, zero means,
// AND transpose x -> bf16 [25600][128]. Grid = 400.
// ---------------------------------------------------------------------------
__global__ __launch_bounds__(256) void prep_kernel(
    const unsigned short* __restrict__ xp,
    const void* pwin, const void* pwid, const void* pwgat, const void* pwout,
    const void* pasrc, const void* padst, const void* pgbias,
    const void* pbng, const void* pbnb, const void* pbnm, const void* pbnv,
    const void* psew1, const void* pseb1, const void* psew2, const void* pseb2,
    unsigned short* __restrict__ wb, float* __restrict__ cvt,
    float* __restrict__ means, unsigned short* __restrict__ xT)
{
    __shared__ unsigned short T[64 * 136];
    const bool f32 = probe_f32(xp);
    const int tid = threadIdx.x;
    const int bid = blockIdx.x;
    const int gid = bid * 256 + tid;
    const int stride = gridDim.x * 256;

    if (bid == 0) means[tid] = 0.f;

    for (int i = gid; i < B_WEND; i += stride) {
        const void* s; int o;
        if      (i < B_WID)   { s = pwin;  o = i - B_WIN; }
        else if (i < B_WGAT)  { s = pwid;  o = i - B_WID; }
        else if (i < B_WOUT)  { s = pwgat; o = i - B_WGAT; }
        else                  { s = pwout; o = i - B_WOUT; }
        wb[i] = f32 ? f2b(((const float*)s)[o]) : ((const unsigned short*)s)[o];
    }
    for (int i = gid; i < 512; i += stride) {
        float sc = ldf(pbng, i, f32) * rsqrtf(ldf(pbnv, i, f32) + 1e-5f);
        cvt[C_BNA + i] = sc;
        cvt[C_BNB + i] = (ldf(pgbias, i, f32) - ldf(pbnm, i, f32)) * sc + ldf(pbnb, i, f32);
        cvt[C_ASRC + i] = ldf(pasrc, i, f32);
        cvt[C_ADST + i] = ldf(padst, i, f32);
    }
    for (int i = gid; i < 16384; i += stride) {
        cvt[C_SEW1 + i] = ldf(psew1, i, f32);
        cvt[C_SEW2 + i] = ldf(psew2, i, f32);
    }
    for (int i = gid; i < 64; i += stride)  cvt[C_SEB1 + i] = ldf(pseb1, i, f32);
    for (int i = gid; i < 256; i += stride) cvt[C_SEB2 + i] = ldf(pseb2, i, f32);

    // transpose slice: 64 nodes per block
    {
        const int n0 = bid * 64;
        const int nl = tid & 63;
#pragma unroll
        for (int i = 0; i < 32; ++i) {
            int c = i * 4 + (tid >> 6);
            long idx = (long)c * NN + n0 + nl;
            T[nl * 136 + c] = f32 ? f2b(((const float*)xp)[idx]) : xp[idx];
        }
        __syncthreads();
#pragma unroll
        for (int i = 0; i < 4; ++i) {
            int n = tid >> 2, c0 = (tid & 3) * 32 + i * 8;
            uint4 v = *(const uint4*)&T[n * 136 + c0];
            *(uint4*)(xT + (long)(n0 + n) * 128 + c0) = v;
        }
    }
}

// ---------------------------------------------------------------------------
// LDS layouts
// ---------------------------------------------------------------------------
struct SmemG2 { unsigned short As[128*40], Bi[64*40], Bd[64*40]; }; // 20480 B
struct SmemC  { unsigned short Cs[128*72]; };                       // 18432 B
union  SmemX2 { SmemG2 s; SmemC c; };

struct SmemFG { unsigned short As[128*40], Bs[256*40]; };           // 30720 B
struct SmemFA { float es[128][11][8]; };                            // 45056 B
union  SmemF  { SmemFG g; SmemFA a; SmemC c; };

// ---------------------------------------------------------------------------
// MFMA GEMM (dual-B, K=128): xf16=A@Wi^T, idb16=A@Wd^T (both bf16).
// Coalesced C stores via LDS staging. Grid (200,4), 256 thr.
// ---------------------------------------------------------------------------
__global__ __launch_bounds__(256) void mfma_gemm_x2_kernel(
    const unsigned short* __restrict__ A16,
    const unsigned short* __restrict__ Wi16,
    const unsigned short* __restrict__ Wd16,
    unsigned short* __restrict__ xf16,
    unsigned short* __restrict__ idb16)
{
    __shared__ SmemX2 sm;
    const int tid = threadIdx.x;
    const int m0 = blockIdx.x * 128, o0 = blockIdx.y * 64;
    const int lane = tid & 63, wv = tid >> 6;
    const int wm = wv >> 1, wn = wv & 1;
    const int lr = lane & 15, quad = lane >> 4;

    ffrag ai[4][2], ad[4][2];
#pragma unroll
    for (int mt = 0; mt < 4; ++mt)
#pragma unroll
        for (int nt = 0; nt < 2; ++nt) { ai[mt][nt] = (ffrag){0,0,0,0}; ad[mt][nt] = (ffrag){0,0,0,0}; }

    for (int k0 = 0; k0 < 128; k0 += 32) {
#pragma unroll
        for (int c = tid; c < 512; c += 256) {
            int row = c >> 2, q = c & 3;
            uint4 v = *(const uint4*)(A16 + (long)(m0 + row) * 128 + k0 + q * 8);
            *(uint4*)&sm.s.As[row * 40 + q * 8] = v;
        }
        {
            int row = tid >> 2, q = tid & 3;
            uint4 vi = *(const uint4*)(Wi16 + (long)(o0 + row) * 128 + k0 + q * 8);
            uint4 vd = *(const uint4*)(Wd16 + (long)(o0 + row) * 128 + k0 + q * 8);
            *(uint4*)&sm.s.Bi[row * 40 + q * 8] = vi;
            *(uint4*)&sm.s.Bd[row * 40 + q * 8] = vd;
        }
        __syncthreads();
        bfrag a[4], bi[2], bd[2];
#pragma unroll
        for (int mt = 0; mt < 4; ++mt)
            a[mt] = *(const bfrag*)&sm.s.As[(wm * 64 + mt * 16 + lr) * 40 + quad * 8];
#pragma unroll
        for (int nt = 0; nt < 2; ++nt) {
            bi[nt] = *(const bfrag*)&sm.s.Bi[(wn * 32 + nt * 16 + lr) * 40 + quad * 8];
            bd[nt] = *(const bfrag*)&sm.s.Bd[(wn * 32 + nt * 16 + lr) * 40 + quad * 8];
        }
#pragma unroll
        for (int mt = 0; mt < 4; ++mt)
#pragma unroll
            for (int nt = 0; nt < 2; ++nt) {
                ai[mt][nt] = __builtin_amdgcn_mfma_f32_16x16x32_bf16(a[mt], bi[nt], ai[mt][nt], 0, 0, 0);
                ad[mt][nt] = __builtin_amdgcn_mfma_f32_16x16x32_bf16(a[mt], bd[nt], ad[mt][nt], 0, 0, 0);
            }
        __syncthreads();
    }
    // epilogue 1: xf16
#pragma unroll
    for (int mt = 0; mt < 4; ++mt)
#pragma unroll
        for (int nt = 0; nt < 2; ++nt)
#pragma unroll
            for (int r = 0; r < 4; ++r)
                sm.c.Cs[(wm * 64 + mt * 16 + quad * 4 + r) * 72 + wn * 32 + nt * 16 + lr] = f2b(ai[mt][nt][r]);
    __syncthreads();
#pragma unroll
    for (int it = 0; it < 4; ++it) {
        int e = it * 256 + tid;
        int row = e >> 3, c8 = (e & 7) * 8;
        *(uint4*)(xf16 + (long)(m0 + row) * C2 + o0 + c8) = *(const uint4*)&sm.c.Cs[row * 72 + c8];
    }
    __syncthreads();
    // epilogue 2: idb16
#pragma unroll
    for (int mt = 0; mt < 4; ++mt)
#pragma unroll
        for (int nt = 0; nt < 2; ++nt)
#pragma unroll
            for (int r = 0; r < 4; ++r)
                sm.c.Cs[(wm * 64 + mt * 16 + quad * 4 + r) * 72 + wn * 32 + nt * 16 + lr] = f2b(ad[mt][nt][r]);
    __syncthreads();
#pragma unroll
    for (int it = 0; it < 4; ++it) {
        int e = it * 256 + tid;
        int row = e >> 3, c8 = (e & 7) * 8;
        *(uint4*)(idb16 + (long)(m0 + row) * C2 + o0 + c8) = *(const uint4*)&sm.c.Cs[row * 72 + c8];
    }
}

// ---------------------------------------------------------------------------
// Fused GAT kernel. Grid 200, 512 threads (8 waves), tile 128 rows x 256 cols.
//  Optional prologue (h_in != null): aggregate previous hop into this block's
//  128 rows of xf16 (softmax alpha in LDS, 11-neighbor gather, BN+ReLU+res),
//  write xf16 (block-own rows only), then GEMM A is read back L2-hot.
//  GEMM: C = A[128x256] @ W^T (W row-major [256 out][256 in]).
//  mode 1: attention epilogue -> als_out/ald_out.  mode 2: colsum -> means.
// ---------------------------------------------------------------------------
__global__ __launch_bounds__(512) void fused_gat_kernel(
    unsigned short* __restrict__ xf16,        // A source; agg residual + write target
    const unsigned short* __restrict__ h_in,  // null => skip aggregation
    const float* __restrict__ als_in, const float* __restrict__ ald_in,
    const float* __restrict__ bnA, const float* __restrict__ bnB,
    const unsigned short* __restrict__ W16,
    unsigned short* __restrict__ Cout,
    const float* __restrict__ asrc, const float* __restrict__ adst,
    float* __restrict__ als_out, float* __restrict__ ald_out,
    float* __restrict__ means, int mode)
{
    __shared__ SmemF sm;
    const int tid = threadIdx.x;
    const int m0 = blockIdx.x * 128;
    const int lane = tid & 63, wv = tid >> 6;
    const int wm = wv >> 2, wn = wv & 3;          // 2 x 4 waves
    const int lr = lane & 15, quad = lane >> 4;

    const int SI[11] = { 1, 1, 1, 0, 0, -1, -1, -1, -2,  0, 0};
    const int SJ[11] = { 1, 0,-1, 1,-1,  1,  0, -1,  0, -2, 0};

    if (h_in) {
        // ---- phase A1: neighbor al_s into LDS ----
        for (int idx = tid; idx < 11264; idx += 512) {
            int ln = idx / 88, rem = idx - ln * 88;
            int k = rem >> 3, hh = rem & 7;
            int n2 = m0 + ln, ii = n2 / WW, jj = n2 - ii * WW;
            int si = ii + SI[k], sj = jj + SJ[k];
            bool ok = (si >= 0) & (si < HH) & (sj >= 0) & (sj < WW);
            sm.a.es[ln][k][hh] = ok ? als_in[(si * WW + sj) * 8 + hh] : -1e30f;
        }
        __syncthreads();
        // ---- phase A2: per (node, head) softmax, alpha in-place ----
        for (int p = tid; p < 1024; p += 512) {
            int ln = p >> 3, hd = p & 7;
            float ad = ald_in[(m0 + ln) * 8 + hd];
            float e[11];
            float mx = -1e30f;
#pragma unroll
            for (int k = 0; k < 11; ++k) {
                float v = sm.a.es[ln][k][hd] + ad;
                v = v > 0.f ? v : 0.2f * v;
                e[k] = v;
                mx = fmaxf(mx, v);
            }
            float den = 0.f;
#pragma unroll
            for (int k = 0; k < 11; ++k) { float q = __expf(e[k] - mx); e[k] = q; den += q; }
            float inv = 1.f / (den + 1e-16f);
#pragma unroll
            for (int k = 0; k < 11; ++k) sm.a.es[ln][k][hd] = e[k] * inv;
        }
        __syncthreads();
        // ---- phase A3: gather h, BN+ReLU+residual, write xf16 (own rows) ----
        {
            const int cj = tid & 31, c8 = cj * 8, hd = cj >> 2;
            for (int q = 0; q < 8; ++q) {
                int ln = q * 16 + (tid >> 5);
                int n = m0 + ln, i = n / WW, j = n - i * WW;
                float acc8[8] = {0,0,0,0,0,0,0,0};
#pragma unroll
                for (int k = 0; k < 11; ++k) {
                    int si = i + SI[k], sj = j + SJ[k];
                    bool ok = (si >= 0) & (si < HH) & (sj >= 0) & (sj < WW);
                    int srcn = ok ? si * WW + sj : n;
                    float al = sm.a.es[ln][k][hd];
                    uint4 hv = *(const uint4*)(h_in + (long)srcn * C2 + c8);
                    acc8[0] += al * lo16f(hv.x); acc8[1] += al * hi16f(hv.x);
                    acc8[2] += al * lo16f(hv.y); acc8[3] += al * hi16f(hv.y);
                    acc8[4] += al * lo16f(hv.z); acc8[5] += al * hi16f(hv.z);
                    acc8[6] += al * lo16f(hv.w); acc8[7] += al * hi16f(hv.w);
                }
                uint4 rv = *(const uint4*)(xf16 + (long)n * C2 + c8);
                float res[8] = {lo16f(rv.x),hi16f(rv.x),lo16f(rv.y),hi16f(rv.y),
                                lo16f(rv.z),hi16f(rv.z),lo16f(rv.w),hi16f(rv.w)};
                unsigned short o[8];
#pragma unroll
                for (int q2 = 0; q2 < 8; ++q2) {
                    int c = c8 + q2;
                    float g = acc8[q2] * bnA[c] + bnB[c];
                    o[q2] = f2b(fmaxf(g, 0.f) + res[q2]);
                }
                uint4 ov;
                ov.x = (unsigned int)o[0] | ((unsigned int)o[1] << 16);
                ov.y = (unsigned int)o[2] | ((unsigned int)o[3] << 16);
                ov.z = (unsigned int)o[4] | ((unsigned int)o[5] << 16);
                ov.w = (unsigned int)o[6] | ((unsigned int)o[7] << 16);
                *(uint4*)(xf16 + (long)n * C2 + c8) = ov;
            }
        }
        __syncthreads();   // drain xf writes + free LDS for GEMM staging
    }

    // ---- GEMM: acc[4][4] per wave (64x64 wave tile), K=256 ----
    ffrag acc[4][4];
#pragma unroll
    for (int mt = 0; mt < 4; ++mt)
#pragma unroll
        for (int nt = 0; nt < 4; ++nt) acc[mt][nt] = (ffrag){0,0,0,0};

    for (int k0 = 0; k0 < 256; k0 += 32) {
        {   // As: 128 rows x 32 ch = 512 uint4, one per thread
            int row = tid >> 2, q = tid & 3;
            uint4 v = *(const uint4*)(xf16 + (long)(m0 + row) * C2 + k0 + q * 8);
            *(uint4*)&sm.g.As[row * 40 + q * 8] = v;
        }
#pragma unroll
        for (int c = tid; c < 1024; c += 512) {  // Bs: 256 rows x 32 ch
            int row = c >> 2, q = c & 3;
            uint4 v = *(const uint4*)(W16 + (long)row * C2 + k0 + q * 8);
            *(uint4*)&sm.g.Bs[row * 40 + q * 8] = v;
        }
        __syncthreads();
        bfrag a[4], b[4];
#pragma unroll
        for (int mt = 0; mt < 4; ++mt)
            a[mt] = *(const bfrag*)&sm.g.As[(wm * 64 + mt * 16 + lr) * 40 + quad * 8];
#pragma unroll
        for (int nt = 0; nt < 4; ++nt)
            b[nt] = *(const bfrag*)&sm.g.Bs[(wn * 64 + nt * 16 + lr) * 40 + quad * 8];
#pragma unroll
        for (int mt = 0; mt < 4; ++mt)
#pragma unroll
            for (int nt = 0; nt < 4; ++nt)
                acc[mt][nt] = __builtin_amdgcn_mfma_f32_16x16x32_bf16(a[mt], b[nt], acc[mt][nt], 0, 0, 0);
        __syncthreads();
    }

    if (mode == 1) {
        // attention epilogue: head = wn*2 + hh; cols head*32 + {lo16, hi16}
#pragma unroll
        for (int hh = 0; hh < 2; ++hh) {
            const int head = wn * 2 + hh;
            const float as_lo = asrc[head * 32 + lr], as_hi = asrc[head * 32 + 16 + lr];
            const float ad_lo = adst[head * 32 + lr], ad_hi = adst[head * 32 + 16 + lr];
#pragma unroll
            for (int mt = 0; mt < 4; ++mt)
#pragma unroll
                for (int r = 0; r < 4; ++r) {
                    float ps = acc[mt][2*hh][r] * as_lo + acc[mt][2*hh+1][r] * as_hi;
                    float pd = acc[mt][2*hh][r] * ad_lo + acc[mt][2*hh+1][r] * ad_hi;
#pragma unroll
                    for (int sh = 1; sh < 16; sh <<= 1) {
                        ps += __shfl_xor(ps, sh);
                        pd += __shfl_xor(pd, sh);
                    }
                    if (lr == 0) {
                        int m = m0 + wm * 64 + mt * 16 + quad * 4 + r;
                        als_out[m * 8 + head] = ps;
                        ald_out[m * 8 + head] = pd;
                    }
                }
        }
    } else if (mode == 2) {
#pragma unroll
        for (int nt = 0; nt < 4; ++nt) {
            float p = 0.f;
#pragma unroll
            for (int mt = 0; mt < 4; ++mt)
#pragma unroll
                for (int r = 0; r < 4; ++r) p += acc[mt][nt][r];
            p += __shfl_xor(p, 16);
            p += __shfl_xor(p, 32);
            if (quad == 0) atomicAdd(&means[wn * 64 + nt * 16 + lr], p);
        }
    }

    // ---- C store via LDS, 4 passes of 64 cols ----
#pragma unroll
    for (int pc = 0; pc < 4; ++pc) {
        if (wn == pc) {
#pragma unroll
            for (int mt = 0; mt < 4; ++mt)
#pragma unroll
                for (int nt = 0; nt < 4; ++nt)
#pragma unroll
                    for (int r = 0; r < 4; ++r)
                        sm.c.Cs[(wm * 64 + mt * 16 + quad * 4 + r) * 72 + nt * 16 + lr] = f2b(acc[mt][nt][r]);
        }
        __syncthreads();
#pragma unroll
        for (int it = 0; it < 2; ++it) {
            int e = it * 512 + tid;
            int row = e >> 3, c8 = (e & 7) * 8;
            *(uint4*)(Cout + (long)(m0 + row) * C2 + pc * 64 + c8) = *(const uint4*)&sm.c.Cs[row * 72 + c8];
        }
        __syncthreads();
    }
}

// ---------------------------------------------------------------------------
// Final: SE vector from means (redundant per block), then
// out[c][n] = y[n][c]*s[c] + id[n][c] (transposed store; dtype by probe).
// ---------------------------------------------------------------------------
__global__ __launch_bounds__(256) void final_kernel(
    const unsigned short* __restrict__ x_probe,
    const unsigned short* __restrict__ y16,
    const unsigned short* __restrict__ idb16,
    const float* __restrict__ means,
    const float* __restrict__ cvt,
    void* __restrict__ outp)
{
    __shared__ float T[64][65];
    __shared__ float mv[256];
    __shared__ float hv[64];
    __shared__ float sv[64];
    const bool f32o = probe_f32(x_probe);
    const int t = threadIdx.x;
    const int n0 = blockIdx.x * 64, c0 = blockIdx.y * 64;

    mv[t] = means[t] * (1.0f / 25600.0f);
    __syncthreads();
    if (t < 64) {
        const float* w1 = cvt + C_SEW1 + t * 256;
        float s = cvt[C_SEB1 + t];
        for (int cc = 0; cc < 256; cc += 4) {
            float4 wv = *(const float4*)(w1 + cc);
            s += wv.x * mv[cc] + wv.y * mv[cc+1] + wv.z * mv[cc+2] + wv.w * mv[cc+3];
        }
        hv[t] = fmaxf(s, 0.f);
    }
    __syncthreads();
    if (t < 64) {
        const int c = c0 + t;
        const float* w2 = cvt + C_SEW2 + c * 64;
        float s = cvt[C_SEB2 + c];
        for (int k = 0; k < 64; k += 4) {
            float4 wv = *(const float4*)(w2 + k);
            s += wv.x * hv[k] + wv.y * hv[k+1] + wv.z * hv[k+2] + wv.w * hv[k+3];
        }
        sv[t] = 1.0f / (1.0f + __expf(-s));
    }
    __syncthreads();
#pragma unroll
    for (int it = 0; it < 16; ++it) {
        int e = t + it * 256;
        int nn = e >> 6, cc = e & 63;
        long idx = (long)(n0 + nn) * C2 + c0 + cc;
        T[cc][nn] = b2f(y16[idx]) * sv[cc] + b2f(idb16[idx]);
    }
    __syncthreads();
#pragma unroll
    for (int it = 0; it < 16; ++it) {
        int e = t + it * 256;
        int cc = e >> 6, nn = e & 63;
        long idx = (long)(c0 + cc) * NN + n0 + nn;
        float v = T[cc][nn];
        if (f32o) ((float*)outp)[idx] = v;
        else      ((unsigned short*)outp)[idx] = f2b(v);
    }
}

extern "C" void kernel_launch(void* const* d_in, const int* in_sizes, int n_in,
                              void* d_out, int out_size, void* d_ws, size_t ws_size,
                              hipStream_t stream) {
    float* ws = (float*)d_ws;
    float* cvt   = ws;                          // C_END small fp32 params
    float* means = ws + 35200;                  // 256 (64-aligned)
    float* als1  = means + 256;                 // 204800
    float* ald1  = als1 + 204800;
    float* als2  = ald1 + 204800;
    float* ald2  = als2 + 204800;
    unsigned short* wb16  = (unsigned short*)(ald2 + 204800);  // 262144
    unsigned short* xT16  = wb16 + B_WEND;                     // 25600*128
    unsigned short* xf16  = xT16 + NN * 128;                   // 25600*256 (xf, rewritten per hop)
    unsigned short* h1    = xf16 + NN * 256;                   // 25600*256 (h hop1 / y)
    unsigned short* h2    = h1 + NN * 256;                     // 25600*256 (h hop2)
    unsigned short* idb16 = h2 + NN * 256;                     // 25600*256

    const unsigned short* xp = (const unsigned short*)d_in[0];

    dim3 b256(256);
    dim3 b512(512);
    dim3 gmfma(NN / 128, C2 / 64);     // 200 x 4
    dim3 gfus(NN / 128);               // 200
    dim3 gfin(NN / 64, C2 / 64);       // 400 x 4

    prep_kernel<<<400, b256, 0, stream>>>(
        xp, d_in[2], d_in[1], d_in[3], d_in[11],
        d_in[4], d_in[5], d_in[6], d_in[7], d_in[8], d_in[9], d_in[10],
        d_in[12], d_in[13], d_in[14], d_in[15],
        wb16, cvt, means, xT16);

    mfma_gemm_x2_kernel<<<gmfma, b256, 0, stream>>>(
        xT16, wb16 + B_WIN, wb16 + B_WID, xf16, idb16);

    // hop 1 GEMM + attention scores (no aggregation prologue)
    fused_gat_kernel<<<gfus, b512, 0, stream>>>(
        xf16, nullptr, nullptr, nullptr, nullptr, nullptr,
        wb16 + B_WGAT, h1,
        cvt + C_ASRC, cvt + C_ADST, als1, ald1, nullptr, 1);

    // aggregate hop1 -> xf, then hop 2 GEMM + attention scores
    fused_gat_kernel<<<gfus, b512, 0, stream>>>(
        xf16, h1, als1, ald1, cvt + C_BNA, cvt + C_BNB,
        wb16 + B_WGAT + 65536, h2,
        cvt + C_ASRC + 256, cvt + C_ADST + 256, als2, ald2, nullptr, 1);

    // aggregate hop2 -> xf, then w_out GEMM + means colsum
    fused_gat_kernel<<<gfus, b512, 0, stream>>>(
        xf16, h2, als2, ald2, cvt + C_BNA + 256, cvt + C_BNB + 256,
        wb16 + B_WOUT, h1,
        nullptr, nullptr, nullptr, nullptr, means, 2);

    final_kernel<<<gfin, b256, 0, stream>>>(xp, h1, idb16, means, cvt, d_out);
}